// Round 1
// baseline (115.973 us; speedup 1.0000x reference)
//
#include <hip/hip_runtime.h>

// Problem constants (from reference)
#define NB   4096
#define NP   16
#define NT   8
#define IND  128
#define OUTD 128

typedef __attribute__((ext_vector_type(4))) float f32x4;
typedef __attribute__((ext_vector_type(8))) short short8;
typedef __attribute__((ext_vector_type(4))) short short4v;

__device__ __forceinline__ unsigned short f2bf(float f) {
  unsigned int u = __float_as_uint(f);
  u = (u + 0x7FFFu + ((u >> 16) & 1u)) >> 16;
  return (unsigned short)u;
}

// LDS layout (bytes):
//   A   : bf16 [128][136]  [0, 34816)        emb rows (p*8+t), padded stride 272B
//   W   : bf16 [256][136]  [34816, 104448)   row n<128: conv_w[o=n][i][0]; n>=128: conv_w[o=n-128][i][1]
//   Y2  : f32  [128][132]  overlay [0,67584) (written after GEMM; A+W dead)
//   red : f32  [2][128]    [104448, 105472)
#define LDS_BYTES 105472
#define ROW_STRIDE 272
#define W_OFF 34816
#define Y2_STRIDE 132
#define RED_OFF 104448

__global__ __launch_bounds__(512)
void path_emb_kernel(const int* __restrict__ path_input,
                     const int* __restrict__ path_type,
                     const float* __restrict__ t0, const float* __restrict__ t1,
                     const float* __restrict__ t2, const float* __restrict__ t3,
                     const float* __restrict__ conv_w,
                     const float* __restrict__ conv_b,
                     float* __restrict__ out)
{
  __shared__ __align__(16) char lds[LDS_BYTES];
  const int b   = blockIdx.x;
  const int tid = threadIdx.x;

  // ---- Stage A: gather embeddings -> bf16 LDS [128][136]
  {
    const int rbase = tid >> 4;       // 0..31 (row within pass)
    const int c8    = (tid & 15) * 8; // 8 floats per thread
    const float* src[4];
#pragma unroll
    for (int pass = 0; pass < 4; ++pass) {
      int row = pass * 32 + rbase;
      int idx = path_input[b * 128 + row];
      int ty  = path_type[row & 7];
      const float* tab = (ty == 0) ? t0 : (ty == 1) ? t1 : (ty == 2) ? t2 : t3;
      src[pass] = tab + (size_t)idx * IND + c8;
    }
    f32x4 v0[4], v1[4];
#pragma unroll
    for (int pass = 0; pass < 4; ++pass) {
      v0[pass] = *(const f32x4*)(src[pass]);
      v1[pass] = *(const f32x4*)(src[pass] + 4);
    }
#pragma unroll
    for (int pass = 0; pass < 4; ++pass) {
      int row = pass * 32 + rbase;
      short8 s;
#pragma unroll
      for (int j = 0; j < 4; ++j) {
        s[j]     = (short)f2bf(v0[pass][j]);
        s[4 + j] = (short)f2bf(v1[pass][j]);
      }
      *(short8*)(lds + row * ROW_STRIDE + c8 * 2) = s;
    }
  }

  // ---- Stage W: conv_w (f32 [128][128][2]) -> bf16 LDS [256][136]
  {
#pragma unroll
    for (int pass = 0; pass < 8; ++pass) {
      int task = pass * 512 + tid;  // 4096 tasks
      int o    = task >> 5;         // 0..127
      int ig   = task & 31;         // i = ig*4
      const float* s = conv_w + o * 256 + ig * 8;  // 8 consecutive floats = 4 (i,k) pairs
      f32x4 w0 = *(const f32x4*)(s);
      f32x4 w1 = *(const f32x4*)(s + 4);
      short4v k0, k1;
      k0[0] = (short)f2bf(w0[0]); k1[0] = (short)f2bf(w0[1]);
      k0[1] = (short)f2bf(w0[2]); k1[1] = (short)f2bf(w0[3]);
      k0[2] = (short)f2bf(w1[0]); k1[2] = (short)f2bf(w1[1]);
      k0[3] = (short)f2bf(w1[2]); k1[3] = (short)f2bf(w1[3]);
      *(short4v*)(lds + W_OFF + o * ROW_STRIDE + ig * 8)          = k0;
      *(short4v*)(lds + W_OFF + (o + 128) * ROW_STRIDE + ig * 8)  = k1;
    }
  }
  __syncthreads();

  // ---- GEMM: Y[128][256] = A[128][128] @ W^T ; 8 waves, 64x64 tiles
  const int wid  = tid >> 6;
  const int lane = tid & 63;
  const int lrow = lane & 15;
  const int lk   = lane >> 4;       // k-group 0..3
  const int R = wid & 1;            // row half
  const int C = wid >> 1;           // col quarter 0..3

  f32x4 acc[4][4] = {};
  const int arow0 = R * 64 + lrow;
  const int wrow0 = C * 64 + lrow;
#pragma unroll
  for (int kk = 0; kk < 4; ++kk) {
    const int kb = kk * 64 + lk * 16;  // byte offset of k-slice within a row
    short8 a[4], bb[4];
#pragma unroll
    for (int m = 0; m < 4; ++m)
      a[m] = *(const short8*)(lds + (arow0 + m * 16) * ROW_STRIDE + kb);
#pragma unroll
    for (int n = 0; n < 4; ++n)
      bb[n] = *(const short8*)(lds + W_OFF + (wrow0 + n * 16) * ROW_STRIDE + kb);
#pragma unroll
    for (int m = 0; m < 4; ++m)
#pragma unroll
      for (int n = 0; n < 4; ++n)
        acc[m][n] = __builtin_amdgcn_mfma_f32_16x16x32_bf16(a[m], bb[n], acc[m][n], 0, 0, 0);
  }

  __syncthreads();  // all waves done reading A/W before overlaying Y2

  // ---- Epilogue part 1: Y2 (cols 128..255) -> LDS f32 [128][132]
  float* Y2 = (float*)lds;
  if (C >= 2) {
    const int cb = (C - 2) * 64;
#pragma unroll
    for (int m = 0; m < 4; ++m)
#pragma unroll
      for (int n = 0; n < 4; ++n)
#pragma unroll
        for (int r = 0; r < 4; ++r) {
          int row = R * 64 + m * 16 + lk * 4 + r;  // D: row=(lane>>4)*4+reg
          int col = cb + n * 16 + lrow;            // D: col=lane&15
          Y2[row * Y2_STRIDE + col] = acc[m][n][r];
        }
  }
  __syncthreads();

  // ---- Epilogue part 2: win[r] = Y1[r] + Y2[r+1]; max over valid rows
  float* red = (float*)(lds + RED_OFF);
  if (C < 2) {
    float vmax[4] = {-1e30f, -1e30f, -1e30f, -1e30f};
#pragma unroll
    for (int m = 0; m < 4; ++m)
#pragma unroll
      for (int n = 0; n < 4; ++n)
#pragma unroll
        for (int r = 0; r < 4; ++r) {
          int row = R * 64 + m * 16 + lk * 4 + r;
          if ((row & 7) != 7) {  // t in [0,7): valid window
            int col = C * 64 + n * 16 + lrow;
            float w = acc[m][n][r] + Y2[(row + 1) * Y2_STRIDE + col];
            vmax[n] = fmaxf(vmax[n], w);
          }
        }
#pragma unroll
    for (int n = 0; n < 4; ++n) {
      float v = vmax[n];
      v = fmaxf(v, __shfl_xor(v, 16));
      v = fmaxf(v, __shfl_xor(v, 32));
      vmax[n] = v;
    }
    if (lane < 16) {
#pragma unroll
      for (int n = 0; n < 4; ++n)
        red[R * 128 + C * 64 + n * 16 + lane] = vmax[n];
    }
  }
  __syncthreads();

  if (tid < 128) {
    float m = fmaxf(red[tid], red[128 + tid]) + conv_b[tid];
    out[(size_t)b * 128 + tid] = m;
  }
}

extern "C" void kernel_launch(void* const* d_in, const int* in_sizes, int n_in,
                              void* d_out, int out_size, void* d_ws, size_t ws_size,
                              hipStream_t stream) {
  const int*   path_input = (const int*)d_in[0];
  // d_in[1] = path_num (16), d_in[2] = timestamp (8): compile-time constants
  const int*   path_type  = (const int*)d_in[3];
  const float* user_emb   = (const float*)d_in[4];
  const float* item_emb   = (const float*)d_in[5];
  const float* ca_emb     = (const float*)d_in[6];
  const float* ci_emb     = (const float*)d_in[7];
  const float* conv_w     = (const float*)d_in[8];
  const float* conv_b     = (const float*)d_in[9];
  float* out = (float*)d_out;

  path_emb_kernel<<<dim3(NB), dim3(512), 0, stream>>>(
      path_input, path_type, user_emb, item_emb, ca_emb, ci_emb,
      conv_w, conv_b, out);
}

// Round 2
// 64.582 us; speedup vs baseline: 1.7957x; 1.7957x over previous
//
#include <hip/hip_runtime.h>

#define NB   4096
#define IND  128
#define OUTD 128

typedef __attribute__((ext_vector_type(4))) float f32x4;
typedef __attribute__((ext_vector_type(8))) short short8;

__device__ __forceinline__ unsigned short f2bf(float f) {
  unsigned int u = __float_as_uint(f);
  u = (u + 0x7FFFu + ((u >> 16) & 1u)) >> 16;
  return (unsigned short)u;
}

// ---------------------------------------------------------------------------
// Pre-kernel: conv_w f32 [o=128][i=128][k=2] -> d_ws bf16 in B-fragment order.
// Fragment id f = ((kk*2 + ker)*8 + ng), lane l: 8 bf16 of
//   col = ng*16 + (l&15),  k = kk*32 + (l>>4)*8 + j   (j=0..7)
// stored at ws + f*1024 + l*16.
// ---------------------------------------------------------------------------
__global__ __launch_bounds__(512)
void wconv_kernel(const float* __restrict__ conv_w, unsigned short* __restrict__ ws)
{
  int flat = blockIdx.x * 512 + threadIdx.x;   // 0..4095
  int lane = flat & 63;
  int ng   = (flat >> 6) & 7;
  int ker  = (flat >> 9) & 1;
  int kk   = flat >> 10;
  int col  = ng * 16 + (lane & 15);
  int k0   = kk * 32 + (lane >> 4) * 8;
  short8 s;
#pragma unroll
  for (int j = 0; j < 8; ++j)
    s[j] = (short)f2bf(conv_w[col * 256 + (k0 + j) * 2 + ker]);
  *(short8*)(ws + (size_t)flat * 8) = s;
}

// ---------------------------------------------------------------------------
// Main kernel: one b per block. 8 waves = 2 row-halves (R) x 4 col-quarters (C).
// Wave tile: 64 rows x 32 cols, dual accumulators (k0,k1).
// LDS: A bf16 [128 rows][272B stride] + red f32 [2][128].
// ---------------------------------------------------------------------------
#define A_STRIDE 272
#define RED_OFF  34816
#define LDS_BYTES (34816 + 1024)

__global__ __launch_bounds__(512, 4)
void path_emb_kernel(const int* __restrict__ path_input,
                     const int* __restrict__ path_type,
                     const float* __restrict__ t0, const float* __restrict__ t1,
                     const float* __restrict__ t2, const float* __restrict__ t3,
                     const unsigned short* __restrict__ wfrag,
                     const float* __restrict__ conv_b,
                     float* __restrict__ out)
{
  __shared__ __align__(16) char lds[LDS_BYTES];
  const int b   = blockIdx.x;
  const int tid = threadIdx.x;

  // ---- Stage A: gather 128 embedding rows -> bf16 LDS [128][272B]
  {
    const int rbase = tid >> 4;        // 0..31
    const int c     = tid & 15;        // 16B chunk id within row
    const float* src[4];
#pragma unroll
    for (int pass = 0; pass < 4; ++pass) {
      int row = pass * 32 + rbase;
      int idx = path_input[b * 128 + row];
      int ty  = path_type[row & 7];
      const float* tab = (ty == 0) ? t0 : (ty == 1) ? t1 : (ty == 2) ? t2 : t3;
      src[pass] = tab + (size_t)idx * IND + c * 8;
    }
    f32x4 v0[4], v1[4];
#pragma unroll
    for (int pass = 0; pass < 4; ++pass) {
      v0[pass] = *(const f32x4*)(src[pass]);
      v1[pass] = *(const f32x4*)(src[pass] + 4);
    }
#pragma unroll
    for (int pass = 0; pass < 4; ++pass) {
      int row = pass * 32 + rbase;
      short8 s;
#pragma unroll
      for (int j = 0; j < 4; ++j) {
        s[j]     = (short)f2bf(v0[pass][j]);
        s[4 + j] = (short)f2bf(v1[pass][j]);
      }
      *(short8*)(lds + row * A_STRIDE + c * 16) = s;
    }
  }
  __syncthreads();

  // ---- GEMM: dual-tap accumulate over same 128 output cols
  const int wid  = tid >> 6;
  const int lane = tid & 63;
  const int lrow = lane & 15;
  const int lk   = lane >> 4;
  const int R = wid & 1;       // row half (64 rows)
  const int C = wid >> 1;      // col quarter (32 cols)

  f32x4 accA[4][2] = {};       // tap k=0: [m][n]
  f32x4 accB[4][2] = {};       // tap k=1
  const int arow0 = R * 64 + lrow;

#pragma unroll
  for (int kk = 0; kk < 4; ++kk) {
    short8 a[4];
#pragma unroll
    for (int m = 0; m < 4; ++m)
      a[m] = *(const short8*)(lds + (arow0 + m * 16) * A_STRIDE + kk * 64 + lk * 16);
    short8 b0[2], b1[2];
#pragma unroll
    for (int n = 0; n < 2; ++n) {
      int f0 = (kk * 2 + 0) * 8 + C * 2 + n;
      int f1 = (kk * 2 + 1) * 8 + C * 2 + n;
      b0[n] = *(const short8*)(wfrag + (size_t)f0 * 512 + lane * 8);
      b1[n] = *(const short8*)(wfrag + (size_t)f1 * 512 + lane * 8);
    }
#pragma unroll
    for (int m = 0; m < 4; ++m)
#pragma unroll
      for (int n = 0; n < 2; ++n) {
        accA[m][n] = __builtin_amdgcn_mfma_f32_16x16x32_bf16(a[m], b0[n], accA[m][n], 0, 0, 0);
        accB[m][n] = __builtin_amdgcn_mfma_f32_16x16x32_bf16(a[m], b1[n], accB[m][n], 0, 0, 0);
      }
  }

  // ---- Epilogue: win[row] = accA[row] + accB[row+1]; max over valid rows.
  // Out-row within 16-row frag = lk*4 + r. Shift: r<3 -> reg r+1; r==3 ->
  // lane+16's reg 0. Rows with (row&7)==7 (lk=1,r=3 / lk=3,r=3) are invalid.
  float* red = (float*)(lds + RED_OFF);
  float vmax[2] = {-1e30f, -1e30f};
#pragma unroll
  for (int m = 0; m < 4; ++m)
#pragma unroll
    for (int n = 0; n < 2; ++n) {
      float up = __shfl_down(accB[m][n][0], 16);   // accB at (lk+1, r=0)
#pragma unroll
      for (int r = 0; r < 4; ++r) {
        int rloc = lk * 4 + r;
        if ((rloc & 7) == 7) continue;             // t==7: no window
        float y2 = (r < 3) ? accB[m][n][r + 1] : up;
        float w  = accA[m][n][r] + y2;
        vmax[n] = fmaxf(vmax[n], w);
      }
    }
#pragma unroll
  for (int n = 0; n < 2; ++n) {
    float v = vmax[n];
    v = fmaxf(v, __shfl_xor(v, 16));
    v = fmaxf(v, __shfl_xor(v, 32));
    vmax[n] = v;
  }
  if (lane < 16) {
#pragma unroll
    for (int n = 0; n < 2; ++n)
      red[R * 128 + C * 32 + n * 16 + lane] = vmax[n];
  }
  __syncthreads();

  if (tid < 128) {
    float m = fmaxf(red[tid], red[128 + tid]) + conv_b[tid];
    out[(size_t)b * 128 + tid] = m;
  }
}

extern "C" void kernel_launch(void* const* d_in, const int* in_sizes, int n_in,
                              void* d_out, int out_size, void* d_ws, size_t ws_size,
                              hipStream_t stream) {
  const int*   path_input = (const int*)d_in[0];
  const int*   path_type  = (const int*)d_in[3];
  const float* user_emb   = (const float*)d_in[4];
  const float* item_emb   = (const float*)d_in[5];
  const float* ca_emb     = (const float*)d_in[6];
  const float* ci_emb     = (const float*)d_in[7];
  const float* conv_w     = (const float*)d_in[8];
  const float* conv_b     = (const float*)d_in[9];
  float* out = (float*)d_out;
  unsigned short* wfrag = (unsigned short*)d_ws;   // 64 KB bf16 fragment buffer

  wconv_kernel<<<dim3(8), dim3(512), 0, stream>>>(conv_w, wfrag);
  path_emb_kernel<<<dim3(NB), dim3(512), 0, stream>>>(
      path_input, path_type, user_emb, item_emb, ca_emb, ci_emb,
      wfrag, conv_b, out);
}

// Round 3
// 56.165 us; speedup vs baseline: 2.0649x; 1.1499x over previous
//
#include <hip/hip_runtime.h>

#define NB   4096
#define NBLK 256
#define NJ   16      // b's per block (NBLK*NJ == NB)

typedef __attribute__((ext_vector_type(4))) float f32x4;
typedef __attribute__((ext_vector_type(8))) short short8;
typedef __attribute__((ext_vector_type(4))) int   int4v;

union Frag { int4v i; short8 s; };

__device__ __forceinline__ unsigned short f2bf(float f) {
  unsigned int u = __float_as_uint(f);
  u = (u + 0x7FFFu + ((u >> 16) & 1u)) >> 16;
  return (unsigned short)u;
}

// ---------------------------------------------------------------------------
// Pre-kernel: conv_w f32 [o=128][i=128][k=2] -> bf16 B-fragments in d_ws.
// Fragment f = ((kk*2 + ker)*8 + ng); lane l holds 8 bf16:
//   col = ng*16 + (l&15),  k = kk*32 + (l>>4)*8 + j (j=0..7)
// at ws + f*1024B + l*16B.   (validated in R1)
// ---------------------------------------------------------------------------
__global__ __launch_bounds__(512)
void wconv_kernel(const float* __restrict__ conv_w, unsigned short* __restrict__ ws)
{
  int flat = blockIdx.x * 512 + threadIdx.x;   // 0..4095
  int lane = flat & 63;
  int ng   = (flat >> 6) & 7;
  int ker  = (flat >> 9) & 1;
  int kk   = flat >> 10;
  int col  = ng * 16 + (lane & 15);
  int k0   = kk * 32 + (lane >> 4) * 8;
  short8 s;
#pragma unroll
  for (int j = 0; j < 8; ++j)
    s[j] = (short)f2bf(conv_w[col * 256 + (k0 + j) * 2 + ker]);
  *(short8*)(ws + (size_t)flat * 8) = s;
}

// ---------------------------------------------------------------------------
// Main kernel. LDS map (bytes):
//   A0 f32 [128 rows][512]   [0,      65536)
//   A1 f32 [128 rows][512]   [65536, 131072)
//   red f32 [2][128]         [131072,132096)
//   idx int [NJ*128]         [132096,140288)
//   ptr8 float* [8]          [140288,140352)
// A row r: 32 16B-units; LDS slot u holds global unit u ^ (r&7)
// (source-address swizzle; global_load_lds dest is linear).
// ---------------------------------------------------------------------------
#define A0_OFF  0
#define A1_OFF  65536
#define RED_OFF 131072
#define IDX_OFF 132096
#define PTR_OFF 140288
#define LDS_BYTES 140352

__global__ __launch_bounds__(512, 2)
void path_emb_kernel(const int* __restrict__ path_input,
                     const int* __restrict__ path_type,
                     const float* __restrict__ t0, const float* __restrict__ t1,
                     const float* __restrict__ t2, const float* __restrict__ t3,
                     const unsigned short* __restrict__ wfrag,
                     const float* __restrict__ conv_b,
                     float* __restrict__ out)
{
  __shared__ __align__(16) char lds[LDS_BYTES];
  const int blk  = blockIdx.x;
  const int tid  = threadIdx.x;
  const int wid  = tid >> 6;
  const int lane = tid & 63;
  const int lrow = lane & 15;
  const int lk   = lane >> 4;
  const int R = wid & 1;      // row half (64 rows)
  const int C = wid >> 1;     // col quarter (32 cols)

  // ---- prologue: indices + table-pointer LUT into LDS
  {
    const int4v* src = (const int4v*)(path_input + (size_t)blk * NJ * 128);
    ((int4v*)(lds + IDX_OFF))[tid] = src[tid];
  }
  if (tid < 8) {
    int ty = path_type[tid];
    const float* tb = (ty == 0) ? t0 : (ty == 1) ? t1 : (ty == 2) ? t2 : t3;
    ((const float**)(lds + PTR_OFF))[tid] = tb;
  }
  float cb = (tid < 128) ? conv_b[tid] : 0.0f;
  __syncthreads();

  // ---- async gather of batch j into LDS buffer (issue only, no wait)
  auto STAGE = [&](int bufoff, int j) {
    const int* idxl = (const int*)(lds + IDX_OFF) + j * 128;
    const float* const* ptr8 = (const float* const*)(lds + PTR_OFF);
#pragma unroll
    for (int i = 0; i < 8; ++i) {
      int r0  = wid * 16 + 2 * i;          // wave-uniform base row (2 rows/instr)
      int row = r0 + (lane >> 5);
      int idx = idxl[row];
      const float* tb = ptr8[row & 7];
      int u = lane & 31;                    // LDS 16B-unit this lane fills
      const float* g = tb + (size_t)idx * 128 + ((u ^ (row & 7)) * 4);
      char* ldst = lds + bufoff + r0 * 512; // wave-uniform; HW adds lane*16
      __builtin_amdgcn_global_load_lds(
          (const __attribute__((address_space(1))) unsigned int*)g,
          (__attribute__((address_space(3))) unsigned int*)ldst, 16, 0, 0);
    }
  };

  // ---- W fragments resident in VGPRs for this wave's column quarter
  Frag wreg[4][2][2];   // [kk][ker][n]
#pragma unroll
  for (int kk = 0; kk < 4; ++kk)
#pragma unroll
    for (int ker = 0; ker < 2; ++ker)
#pragma unroll
      for (int n = 0; n < 2; ++n) {
        int f = (kk * 2 + ker) * 8 + C * 2 + n;
        wreg[kk][ker][n].i = *(const int4v*)(wfrag + (size_t)f * 512 + lane * 8);
      }

  STAGE(A0_OFF, 0);
  __syncthreads();      // drains vmcnt(0): buf0 + wreg ready

  float* red = (float*)(lds + RED_OFF);

  for (int j = 0; j < NJ; ++j) {
    const int bufc = (j & 1) ? A1_OFF : A0_OFF;
    const int bufn = (j & 1) ? A0_OFF : A1_OFF;
    if (j + 1 < NJ) STAGE(bufn, j + 1);   // in flight across the whole iter

    // ---- GEMM from f32 LDS (swizzled read + cvt_pk to bf16)
    f32x4 accA[4][2] = {};
    f32x4 accB[4][2] = {};
    const char* Ab = lds + bufc;
#pragma unroll
    for (int kk = 0; kk < 4; ++kk) {
      Frag a[4];
#pragma unroll
      for (int m = 0; m < 4; ++m) {
        int r  = R * 64 + m * 16 + lrow;
        int u0 = kk * 8 + lk * 2;
        int s  = r & 7;
        f32x4 e0 = *(const f32x4*)(Ab + r * 512 + ((u0 ^ s) * 16));
        f32x4 e1 = *(const f32x4*)(Ab + r * 512 + (((u0 + 1) ^ s) * 16));
        int b0, b1, b2, b3;
        asm("v_cvt_pk_bf16_f32 %0, %1, %2" : "=v"(b0) : "v"(e0[0]), "v"(e0[1]));
        asm("v_cvt_pk_bf16_f32 %0, %1, %2" : "=v"(b1) : "v"(e0[2]), "v"(e0[3]));
        asm("v_cvt_pk_bf16_f32 %0, %1, %2" : "=v"(b2) : "v"(e1[0]), "v"(e1[1]));
        asm("v_cvt_pk_bf16_f32 %0, %1, %2" : "=v"(b3) : "v"(e1[2]), "v"(e1[3]));
        int4v vi; vi[0] = b0; vi[1] = b1; vi[2] = b2; vi[3] = b3;
        a[m].i = vi;
      }
#pragma unroll
      for (int m = 0; m < 4; ++m)
#pragma unroll
        for (int n = 0; n < 2; ++n) {
          accA[m][n] = __builtin_amdgcn_mfma_f32_16x16x32_bf16(
              a[m].s, wreg[kk][0][n].s, accA[m][n], 0, 0, 0);
          accB[m][n] = __builtin_amdgcn_mfma_f32_16x16x32_bf16(
              a[m].s, wreg[kk][1][n].s, accB[m][n], 0, 0, 0);
        }
    }

    // ---- epilogue: win = accA[row] + accB[row+1]; max over valid rows
    float vmax[2] = {-1e30f, -1e30f};
#pragma unroll
    for (int m = 0; m < 4; ++m)
#pragma unroll
      for (int n = 0; n < 2; ++n) {
        float up = __shfl_down(accB[m][n][0], 16);
#pragma unroll
        for (int r = 0; r < 4; ++r) {
          int rloc = lk * 4 + r;
          if ((rloc & 7) == 7) continue;     // t==7: no window
          float y2 = (r < 3) ? accB[m][n][r + 1] : up;
          vmax[n] = fmaxf(vmax[n], accA[m][n][r] + y2);
        }
      }
#pragma unroll
    for (int n = 0; n < 2; ++n) {
      float v = vmax[n];
      v = fmaxf(v, __shfl_xor(v, 16));
      v = fmaxf(v, __shfl_xor(v, 32));
      vmax[n] = v;
    }
    if (lane < 16) {
#pragma unroll
      for (int n = 0; n < 2; ++n)
        red[R * 128 + C * 32 + n * 16 + lane] = vmax[n];
    }

    // lgkm-only barrier: do NOT drain vmcnt (gather for j+1 stays in flight)
    asm volatile("s_waitcnt lgkmcnt(0)" ::: "memory");
    __builtin_amdgcn_sched_barrier(0);
    __builtin_amdgcn_s_barrier();
    __builtin_amdgcn_sched_barrier(0);

    if (tid < 128) {
      volatile float* rv = red;
      float m = fmaxf(rv[tid], rv[128 + tid]) + cb;
      out[(size_t)(blk * NJ + j) * 128 + tid] = m;
    }

    // full drain: gather for j+1 complete; red safe to reuse next iter
    __syncthreads();
  }
}

extern "C" void kernel_launch(void* const* d_in, const int* in_sizes, int n_in,
                              void* d_out, int out_size, void* d_ws, size_t ws_size,
                              hipStream_t stream) {
  const int*   path_input = (const int*)d_in[0];
  const int*   path_type  = (const int*)d_in[3];
  const float* user_emb   = (const float*)d_in[4];
  const float* item_emb   = (const float*)d_in[5];
  const float* ca_emb     = (const float*)d_in[6];
  const float* ci_emb     = (const float*)d_in[7];
  const float* conv_w     = (const float*)d_in[8];
  const float* conv_b     = (const float*)d_in[9];
  float* out = (float*)d_out;
  unsigned short* wfrag = (unsigned short*)d_ws;   // 64 KB bf16 fragment buffer

  wconv_kernel<<<dim3(8), dim3(512), 0, stream>>>(conv_w, wfrag);
  path_emb_kernel<<<dim3(NBLK), dim3(512), 0, stream>>>(
      path_input, path_type, user_emb, item_emb, ca_emb, ci_emb,
      wfrag, conv_b, out);
}

// Round 4
// 52.542 us; speedup vs baseline: 2.2072x; 1.0689x over previous
//
#include <hip/hip_runtime.h>

#define NB   4096
#define NBLK 256
#define NJ   16      // b's per block (NBLK*NJ == NB)

typedef __attribute__((ext_vector_type(4))) float f32x4;
typedef __attribute__((ext_vector_type(8))) short short8;
typedef __attribute__((ext_vector_type(4))) int   int4v;

union Frag { int4v i; short8 s; };

__device__ __forceinline__ unsigned short f2bf(float f) {
  unsigned int u = __float_as_uint(f);
  u = (u + 0x7FFFu + ((u >> 16) & 1u)) >> 16;
  return (unsigned short)u;
}

__device__ __forceinline__ int cvtpk(float lo, float hi) {
  int r;
  asm("v_cvt_pk_bf16_f32 %0, %1, %2" : "=v"(r) : "v"(lo), "v"(hi));
  return r;
}

// ---------------------------------------------------------------------------
// Pre-kernel: conv_w f32 [o=128][i=128][k=2] -> bf16 B-fragments in d_ws.
// Fragment f = ((kk*2 + ker)*8 + ng); lane l holds 8 bf16:
//   col = ng*16 + (l&15),  k = kk*32 + (l>>4)*8 + j (j=0..7)
// at ws + f*1024B + l*16B.   (validated R1/R2)
// ---------------------------------------------------------------------------
__global__ __launch_bounds__(512)
void wconv_kernel(const float* __restrict__ conv_w, unsigned short* __restrict__ ws)
{
  int flat = blockIdx.x * 512 + threadIdx.x;   // 0..4095
  int lane = flat & 63;
  int ng   = (flat >> 6) & 7;
  int ker  = (flat >> 9) & 1;
  int kk   = flat >> 10;
  int col  = ng * 16 + (lane & 15);
  int k0   = kk * 32 + (lane >> 4) * 8;
  short8 s;
#pragma unroll
  for (int j = 0; j < 8; ++j)
    s[j] = (short)f2bf(conv_w[col * 256 + (k0 + j) * 2 + ker]);
  *(short8*)(ws + (size_t)flat * 8) = s;
}

// ---------------------------------------------------------------------------
// Main kernel LDS map (bytes):
//   A0  bf16 [128 rows][272B]   [0,     34816)
//   A1  bf16 [128 rows][272B]   [34816, 69632)
//   RED f32  [2][16][128]       [69632, 86016)   per-(R,j) partial maxes
//   IDX int  [NJ*128]           [86016, 94208)
//   PTR float* [8]              [94208, 94272)
// ---------------------------------------------------------------------------
#define A0_OFF  0
#define A1_OFF  34816
#define RED_OFF 69632
#define IDX_OFF 86016
#define PTR_OFF 94208
#define LDS_BYTES 94272
#define A_STRIDE 272

__global__ __launch_bounds__(512, 2)
void path_emb_kernel(const int* __restrict__ path_input,
                     const int* __restrict__ path_type,
                     const float* __restrict__ t0, const float* __restrict__ t1,
                     const float* __restrict__ t2, const float* __restrict__ t3,
                     const unsigned short* __restrict__ wfrag,
                     const float* __restrict__ conv_b,
                     float* __restrict__ out)
{
  __shared__ __align__(16) char lds[LDS_BYTES];
  const int blk  = blockIdx.x;
  const int tid  = threadIdx.x;
  const int wid  = tid >> 6;
  const int lane = tid & 63;
  const int lrow = lane & 15;
  const int lk   = lane >> 4;
  const int R = wid & 1;      // row half (64 rows)
  const int C = wid >> 1;     // col quarter (32 cols)

  // ---- prologue: indices + table-pointer LUT into LDS
  ((int4v*)(lds + IDX_OFF))[tid] =
      ((const int4v*)(path_input + (size_t)blk * NJ * 128))[tid];
  if (tid < 8) {
    int ty = path_type[tid];
    const float* tb = (ty == 0) ? t0 : (ty == 1) ? t1 : (ty == 2) ? t2 : t3;
    ((const float**)(lds + PTR_OFF))[tid] = tb;
  }

  // ---- W fragments resident in VGPRs (independent of LDS prologue)
  Frag wreg[4][2][2];   // [kk][ker][n]
#pragma unroll
  for (int kk = 0; kk < 4; ++kk)
#pragma unroll
    for (int ker = 0; ker < 2; ++ker)
#pragma unroll
      for (int n = 0; n < 2; ++n) {
        int f = (kk * 2 + ker) * 8 + C * 2 + n;
        wreg[kk][ker][n].i = *(const int4v*)(wfrag + (size_t)f * 512 + lane * 8);
      }
  __syncthreads();  // idx/ptr visible

  // Gather assignment: 4 threads per row; thread covers 32 consecutive f32.
  const int grow = tid >> 2;
  const int gq   = tid & 3;

  auto ISSUE = [&](int j, f32x4 (&ld)[8]) {
    int idx = ((const int*)(lds + IDX_OFF))[j * 128 + grow];
    const float* tb = ((const float* const*)(lds + PTR_OFF))[grow & 7];
    const float* g  = tb + (size_t)idx * 128 + gq * 32;
#pragma unroll
    for (int i = 0; i < 8; ++i) ld[i] = *(const f32x4*)(g + i * 4);
  };
  auto WRITE = [&](int bufoff, const f32x4 (&ld)[8]) {
    char* dst = lds + bufoff + grow * A_STRIDE + gq * 64;
#pragma unroll
    for (int i = 0; i < 4; ++i) {
      int4v w;
      w[0] = cvtpk(ld[2 * i][0], ld[2 * i][1]);
      w[1] = cvtpk(ld[2 * i][2], ld[2 * i][3]);
      w[2] = cvtpk(ld[2 * i + 1][0], ld[2 * i + 1][1]);
      w[3] = cvtpk(ld[2 * i + 1][2], ld[2 * i + 1][3]);
      *(int4v*)(dst + i * 16) = w;
    }
  };

  {
    f32x4 ld0[8];
    ISSUE(0, ld0);
    WRITE(A0_OFF, ld0);
  }
  __syncthreads();

  float* red = (float*)(lds + RED_OFF);
  const int arow0 = R * 64 + lrow;

  for (int j = 0; j < NJ; ++j) {
    const int bufc = (j & 1) ? A1_OFF : A0_OFF;
    const int bufn = (j & 1) ? A0_OFF : A1_OFF;
    const bool pf  = (j + 1 < NJ);

    f32x4 ld[8];
    if (pf) ISSUE(j + 1, ld);          // in flight across the whole GEMM
    __builtin_amdgcn_sched_barrier(0); // keep loads issued here

    // ---- GEMM: dual-tap, bf16 fragments straight from LDS
    f32x4 accA[4][2] = {};
    f32x4 accB[4][2] = {};
    const char* Ab = lds + bufc;
#pragma unroll
    for (int kk = 0; kk < 4; ++kk) {
      Frag a[4];
#pragma unroll
      for (int m = 0; m < 4; ++m)
        a[m].i = *(const int4v*)(Ab + (arow0 + m * 16) * A_STRIDE + kk * 64 + lk * 16);
#pragma unroll
      for (int m = 0; m < 4; ++m)
#pragma unroll
        for (int n = 0; n < 2; ++n) {
          accA[m][n] = __builtin_amdgcn_mfma_f32_16x16x32_bf16(
              a[m].s, wreg[kk][0][n].s, accA[m][n], 0, 0, 0);
          accB[m][n] = __builtin_amdgcn_mfma_f32_16x16x32_bf16(
              a[m].s, wreg[kk][1][n].s, accB[m][n], 0, 0, 0);
        }
    }

    // ---- epilogue: win = accA[row] + accB[row+1]; max over valid rows
    float vmax[2] = {-1e30f, -1e30f};
#pragma unroll
    for (int m = 0; m < 4; ++m)
#pragma unroll
      for (int n = 0; n < 2; ++n) {
        float up = __shfl_down(accB[m][n][0], 16);
#pragma unroll
        for (int r = 0; r < 4; ++r) {
          int rloc = lk * 4 + r;
          if ((rloc & 7) == 7) continue;     // t==7: no window
          float y2 = (r < 3) ? accB[m][n][r + 1] : up;
          vmax[n] = fmaxf(vmax[n], accA[m][n][r] + y2);
        }
      }
#pragma unroll
    for (int n = 0; n < 2; ++n) {
      float v = vmax[n];
      v = fmaxf(v, __shfl_xor(v, 16));
      v = fmaxf(v, __shfl_xor(v, 32));
      vmax[n] = v;
    }
    if (lane < 16) {
#pragma unroll
      for (int n = 0; n < 2; ++n)
        red[R * (NJ * 128) + j * 128 + C * 32 + n * 16 + lane] = vmax[n];
    }

    // ---- stage j+1 into the other buffer (vmcnt wait auto-inserted here)
    if (pf) WRITE(bufn, ld);
    __syncthreads();   // single barrier per iter; no stores outstanding
  }

  // ---- final output: 512 threads x 4 consecutive floats
  {
    const int j  = tid >> 5;
    const int c0 = (tid & 31) * 4;
    const float* redA = (const float*)(lds + RED_OFF);
    const float* redB = redA + NJ * 128;
    f32x4 va = *(const f32x4*)(redA + j * 128 + c0);
    f32x4 vb = *(const f32x4*)(redB + j * 128 + c0);
    f32x4 bb = *(const f32x4*)(conv_b + c0);
    f32x4 o;
#pragma unroll
    for (int k = 0; k < 4; ++k) o[k] = fmaxf(va[k], vb[k]) + bb[k];
    *(f32x4*)(out + (size_t)(blk * NJ + j) * 128 + c0) = o;
  }
}

extern "C" void kernel_launch(void* const* d_in, const int* in_sizes, int n_in,
                              void* d_out, int out_size, void* d_ws, size_t ws_size,
                              hipStream_t stream) {
  const int*   path_input = (const int*)d_in[0];
  const int*   path_type  = (const int*)d_in[3];
  const float* user_emb   = (const float*)d_in[4];
  const float* item_emb   = (const float*)d_in[5];
  const float* ca_emb     = (const float*)d_in[6];
  const float* ci_emb     = (const float*)d_in[7];
  const float* conv_w     = (const float*)d_in[8];
  const float* conv_b     = (const float*)d_in[9];
  float* out = (float*)d_out;
  unsigned short* wfrag = (unsigned short*)d_ws;   // 64 KB bf16 fragment buffer

  wconv_kernel<<<dim3(8), dim3(512), 0, stream>>>(conv_w, wfrag);
  path_emb_kernel<<<dim3(NBLK), dim3(512), 0, stream>>>(
      path_input, path_type, user_emb, item_emb, ca_emb, ci_emb,
      wfrag, conv_b, out);
}

// Round 5
// 51.956 us; speedup vs baseline: 2.2321x; 1.0113x over previous
//
#include <hip/hip_runtime.h>

#define NB   4096
#define NBLK 256
#define NJ   16      // b's per block (NBLK*NJ == NB)

typedef __attribute__((ext_vector_type(4))) float f32x4;
typedef __attribute__((ext_vector_type(8))) short short8;
typedef __attribute__((ext_vector_type(4))) int   int4v;
typedef __attribute__((ext_vector_type(2))) int   int2v;

union Frag { int4v i; short8 s; };

__device__ __forceinline__ unsigned short f2bf(float f) {
  unsigned int u = __float_as_uint(f);
  u = (u + 0x7FFFu + ((u >> 16) & 1u)) >> 16;
  return (unsigned short)u;
}

__device__ __forceinline__ int cvtpk(float lo, float hi) {
  int r;
  asm("v_cvt_pk_bf16_f32 %0, %1, %2" : "=v"(r) : "v"(lo), "v"(hi));
  return r;
}

// ---------------------------------------------------------------------------
// Pre-kernel: conv_w f32 [o=128][i=128][k=2] -> bf16 B-fragments in d_ws.
// Fragment f = ((kk*2 + ker)*8 + ng); lane l holds 8 bf16:
//   col = ng*16 + (l&15),  k = kk*32 + (l>>4)*8 + j (j=0..7)
// at ws + f*1024B + l*16B.   (validated R1-R3)
// ---------------------------------------------------------------------------
__global__ __launch_bounds__(512)
void wconv_kernel(const float* __restrict__ conv_w, unsigned short* __restrict__ ws)
{
  int flat = blockIdx.x * 512 + threadIdx.x;   // 0..4095
  int lane = flat & 63;
  int ng   = (flat >> 6) & 7;
  int ker  = (flat >> 9) & 1;
  int kk   = flat >> 10;
  int col  = ng * 16 + (lane & 15);
  int k0   = kk * 32 + (lane >> 4) * 8;
  short8 s;
#pragma unroll
  for (int j = 0; j < 8; ++j)
    s[j] = (short)f2bf(conv_w[col * 256 + (k0 + j) * 2 + ker]);
  *(short8*)(ws + (size_t)flat * 8) = s;
}

// ---------------------------------------------------------------------------
// Main kernel LDS map (bytes):
//   A0  bf16 [128 rows][272B]   [0,     34816)
//   A1  bf16 [128 rows][272B]   [34816, 69632)
//   RED f32  [2][16][128]       [69632, 86016)
//   IDX int  [NJ*128]           [86016, 94208)
//   PTR float* [8]              [94208, 94272)
// ---------------------------------------------------------------------------
#define A0_OFF  0
#define A1_OFF  34816
#define RED_OFF 69632
#define IDX_OFF 86016
#define PTR_OFF 94208
#define LDS_BYTES 94272
#define A_STRIDE 272

__global__ __launch_bounds__(512, 2)
void path_emb_kernel(const int* __restrict__ path_input,
                     const int* __restrict__ path_type,
                     const float* __restrict__ t0, const float* __restrict__ t1,
                     const float* __restrict__ t2, const float* __restrict__ t3,
                     const unsigned short* __restrict__ wfrag,
                     const float* __restrict__ conv_b,
                     float* __restrict__ out)
{
  __shared__ __align__(16) char lds[LDS_BYTES];
  const int blk  = blockIdx.x;
  const int tid  = threadIdx.x;
  const int wid  = tid >> 6;
  const int lane = tid & 63;
  const int lrow = lane & 15;
  const int lk   = lane >> 4;
  const int R = wid & 1;      // row half (64 rows)
  const int C = wid >> 1;     // col quarter (32 cols)

  // ---- prologue: indices + table-pointer LUT into LDS
  ((int4v*)(lds + IDX_OFF))[tid] =
      ((const int4v*)(path_input + (size_t)blk * NJ * 128))[tid];
  if (tid < 8) {
    int ty = path_type[tid];
    const float* tb = (ty == 0) ? t0 : (ty == 1) ? t1 : (ty == 2) ? t2 : t3;
    ((const float**)(lds + PTR_OFF))[tid] = tb;
  }

  // ---- W fragments resident in VGPRs
  Frag wreg[4][2][2];   // [kk][ker][n]
#pragma unroll
  for (int kk = 0; kk < 4; ++kk)
#pragma unroll
    for (int ker = 0; ker < 2; ++ker)
#pragma unroll
      for (int n = 0; n < 2; ++n) {
        int f = (kk * 2 + ker) * 8 + C * 2 + n;
        wreg[kk][ker][n].i = *(const int4v*)(wfrag + (size_t)f * 512 + lane * 8);
      }
  __syncthreads();  // idx/ptr visible

  // Gather: 4 threads per row; instruction i reads 64B-aligned chunk i of the
  // row, lane gq taking 16 consecutive bytes -> 16 coalesced 64B requests/instr.
  const int grow = tid >> 2;
  const int gq   = tid & 3;

  auto ISSUE = [&](int j, f32x4 (&ld)[8]) {
    int idx = ((const int*)(lds + IDX_OFF))[j * 128 + grow];
    const float* tb = ((const float* const*)(lds + PTR_OFF))[grow & 7];
    const float* g  = tb + (size_t)idx * 128 + gq * 4;
#pragma unroll
    for (int i = 0; i < 8; ++i) ld[i] = *(const f32x4*)(g + i * 16);
  };
  // ld[i] = row floats [i*16 + gq*4, +4) -> bf16 at byte i*32 + gq*8
  auto WRITE = [&](int bufoff, const f32x4 (&ld)[8]) {
    char* dst = lds + bufoff + grow * A_STRIDE + gq * 8;
#pragma unroll
    for (int i = 0; i < 8; ++i) {
      int2v w;
      w[0] = cvtpk(ld[i][0], ld[i][1]);
      w[1] = cvtpk(ld[i][2], ld[i][3]);
      *(int2v*)(dst + i * 32) = w;
    }
  };

  float* red = (float*)(lds + RED_OFF);
  const int arow0 = R * 64 + lrow;

  auto COMPUTE = [&](int bufc, int j) {
    f32x4 accA[4][2] = {};
    f32x4 accB[4][2] = {};
    const char* Ab = lds + bufc;
#pragma unroll
    for (int kk = 0; kk < 4; ++kk) {
      Frag a[4];
#pragma unroll
      for (int m = 0; m < 4; ++m)
        a[m].i = *(const int4v*)(Ab + (arow0 + m * 16) * A_STRIDE + kk * 64 + lk * 16);
#pragma unroll
      for (int m = 0; m < 4; ++m)
#pragma unroll
        for (int n = 0; n < 2; ++n) {
          accA[m][n] = __builtin_amdgcn_mfma_f32_16x16x32_bf16(
              a[m].s, wreg[kk][0][n].s, accA[m][n], 0, 0, 0);
          accB[m][n] = __builtin_amdgcn_mfma_f32_16x16x32_bf16(
              a[m].s, wreg[kk][1][n].s, accB[m][n], 0, 0, 0);
        }
    }
    float vmax[2] = {-1e30f, -1e30f};
#pragma unroll
    for (int m = 0; m < 4; ++m)
#pragma unroll
      for (int n = 0; n < 2; ++n) {
        float up = __shfl_down(accB[m][n][0], 16);
#pragma unroll
        for (int r = 0; r < 4; ++r) {
          int rloc = lk * 4 + r;
          if ((rloc & 7) == 7) continue;     // t==7: no window
          float y2 = (r < 3) ? accB[m][n][r + 1] : up;
          vmax[n] = fmaxf(vmax[n], accA[m][n][r] + y2);
        }
      }
#pragma unroll
    for (int n = 0; n < 2; ++n) {
      float v = vmax[n];
      v = fmaxf(v, __shfl_xor(v, 16));
      v = fmaxf(v, __shfl_xor(v, 32));
      vmax[n] = v;
    }
    if (lane < 16) {
#pragma unroll
      for (int n = 0; n < 2; ++n)
        red[R * (NJ * 128) + j * 128 + C * 32 + n * 16 + lane] = vmax[n];
    }
  };

  // lgkm-only barrier: LDS writes ordered, global loads stay in flight
  auto BAR = [&]() {
    asm volatile("s_waitcnt lgkmcnt(0)" ::: "memory");
    __builtin_amdgcn_sched_barrier(0);
    __builtin_amdgcn_s_barrier();
    __builtin_amdgcn_sched_barrier(0);
  };

  // ---- depth-2 pipeline
  f32x4 ldA[8], ldB[8];
  ISSUE(0, ldA);
  WRITE(A0_OFF, ldA);
  ISSUE(1, ldB);
  BAR();

#pragma unroll 1
  for (int j = 0; j < NJ; j += 2) {
    // even phase: compute A0 (=j); ldA free -> issue j+2; write ldB (=j+1)
    if (j + 2 < NJ) ISSUE(j + 2, ldA);
    __builtin_amdgcn_sched_barrier(0);
    COMPUTE(A0_OFF, j);
    WRITE(A1_OFF, ldB);
    BAR();
    // odd phase: compute A1 (=j+1); ldB free -> issue j+3; write ldA (=j+2)
    if (j + 3 < NJ) ISSUE(j + 3, ldB);
    __builtin_amdgcn_sched_barrier(0);
    COMPUTE(A1_OFF, j + 1);
    if (j + 2 < NJ) WRITE(A0_OFF, ldA);
    BAR();
  }

  // ---- final output: 512 threads x 4 consecutive floats
  {
    const int j  = tid >> 5;
    const int c0 = (tid & 31) * 4;
    const float* redA = (const float*)(lds + RED_OFF);
    const float* redB = redA + NJ * 128;
    f32x4 va = *(const f32x4*)(redA + j * 128 + c0);
    f32x4 vb = *(const f32x4*)(redB + j * 128 + c0);
    f32x4 bb = *(const f32x4*)(conv_b + c0);
    f32x4 o;
#pragma unroll
    for (int k = 0; k < 4; ++k) o[k] = fmaxf(va[k], vb[k]) + bb[k];
    *(f32x4*)(out + (size_t)(blk * NJ + j) * 128 + c0) = o;
  }
}

extern "C" void kernel_launch(void* const* d_in, const int* in_sizes, int n_in,
                              void* d_out, int out_size, void* d_ws, size_t ws_size,
                              hipStream_t stream) {
  const int*   path_input = (const int*)d_in[0];
  const int*   path_type  = (const int*)d_in[3];
  const float* user_emb   = (const float*)d_in[4];
  const float* item_emb   = (const float*)d_in[5];
  const float* ca_emb     = (const float*)d_in[6];
  const float* ci_emb     = (const float*)d_in[7];
  const float* conv_w     = (const float*)d_in[8];
  const float* conv_b     = (const float*)d_in[9];
  float* out = (float*)d_out;
  unsigned short* wfrag = (unsigned short*)d_ws;   // 64 KB bf16 fragment buffer

  wconv_kernel<<<dim3(8), dim3(512), 0, stream>>>(conv_w, wfrag);
  path_emb_kernel<<<dim3(NBLK), dim3(512), 0, stream>>>(
      path_input, path_type, user_emb, item_emb, ca_emb, ci_emb,
      wfrag, conv_b, out);
}